// Round 1
// baseline (68.741 us; speedup 1.0000x reference)
//
#include <hip/hip_runtime.h>

// diagrams: (B=64, D=2, C=8, N=1024, 2) fp32 sorted pairs (birth <= death)
// T = 100 samples t in linspace(0,1,100); K_MAX = 2
// out: (B, D, 2, C*T) fp32 -> flat ((bd*2+k)*C*T + c*T + t)
//
// tri(t) = max(min(t-b, d-t), 0). Clamp absorbed by zero-init of the running
// top-2. Packed fp16 (2 points per VALU op); |err| <= ~1.5e-3 << 9.9e-3.
//
// v2: 512 threads (8 waves) per group-block, each wave scans 128 points for
// all 128 t-slots (t=lane and t=lane+64, second masked at output t<100).
// Rationale: grid is fixed at 1024 blocks (one per group), so occupancy is
// grid-limited; at 128 thr/block only 2 waves/SIMD were resident and LDS /
// dep-chain stalls were exposed. 512 thr -> 32 waves/CU (8/SIMD).
// __launch_bounds__(512, 8) caps VGPR at 64 (live set ~40 with unroll 2).

typedef _Float16 h2 __attribute__((ext_vector_type(2)));

constexpr int T_PTS = 100;
constexpr int NPTS  = 1024;
constexpr int CCH   = 8;
constexpr int NTHR  = 512;
constexpr int NWAVES = NTHR / 64;              // 8
constexpr int U4_PER_WAVE = NPTS / NWAVES / 8; // 16 uint4-pairs (128 pts)

union U4 { uint4 u; h2 h[4]; };

__global__ __launch_bounds__(NTHR, 8) void pl_topk_kernel(
    const float* __restrict__ diagrams, float* __restrict__ out)
{
    const int g  = blockIdx.x;        // (b*D + d)*C + c
    const int c  = g & (CCH - 1);
    const int bd = g >> 3;

    __shared__ alignas(16) h2 bb[NPTS / 2];    // (b[2j], b[2j+1]) fp16
    __shared__ alignas(16) h2 dd[NPTS / 2];    // (d[2j], d[2j+1]) fp16
    __shared__ float hi_s[NWAVES][128];        // per-wave top1 per t-slot
    __shared__ float se_s[NWAVES][128];        // per-wave top2 per t-slot

    // Stage: 512 float4 = 1024 (b,d) pairs -> packed fp16, one load/thread.
    {
        const float4* src4 = (const float4*)(diagrams + (size_t)g * NPTS * 2);
        float4 p = src4[threadIdx.x];              // (b0,d0,b1,d1)
        bb[threadIdx.x] = h2{(_Float16)p.x, (_Float16)p.z};
        dd[threadIdx.x] = h2{(_Float16)p.y, (_Float16)p.w};
    }
    __syncthreads();

    const int lane = threadIdx.x & 63;
    const int w    = threadIdx.x >> 6;

    const _Float16 ta = (_Float16)((float)lane * (1.0f / 99.0f));
    const _Float16 tb = (_Float16)((float)(lane + 64) * (1.0f / 99.0f));
    const h2 ta2 = {ta, ta};
    const h2 tb2 = {tb, tb};

    const h2 z = {(_Float16)0.0f, (_Float16)0.0f};
    h2 m1a = z, m2a = z, m1b = z, m2b = z;     // packed (even,odd) top-2

    const uint4* bb4 = (const uint4*)bb;
    const uint4* dd4 = (const uint4*)dd;
    const int base = w * U4_PER_WAVE;          // wave-uniform -> broadcast reads

    #pragma unroll 2
    for (int i = 0; i < U4_PER_WAVE; ++i) {
        U4 bu, du;
        bu.u = bb4[base + i];                  // ds_read_b128: 8 births
        du.u = dd4[base + i];                  // ds_read_b128: 8 deaths
        #pragma unroll
        for (int j = 0; j < 4; ++j) {
            h2 bj = bu.h[j], dj = du.h[j];
            // stream a (t = lane)
            {
                h2 u   = ta2 - bj;             // v_pk_add (neg)
                h2 v   = dj - ta2;             // v_pk_add (neg)
                h2 tri = __builtin_elementwise_min(u, v);
                h2 lo  = __builtin_elementwise_min(m1a, tri);
                m1a = __builtin_elementwise_max(m1a, tri);
                m2a = __builtin_elementwise_max(m2a, lo);
            }
            // stream b (t = lane + 64)
            {
                h2 u   = tb2 - bj;
                h2 v   = dj - tb2;
                h2 tri = __builtin_elementwise_min(u, v);
                h2 lo  = __builtin_elementwise_min(m1b, tri);
                m1b = __builtin_elementwise_max(m1b, tri);
                m2b = __builtin_elementwise_max(m2b, lo);
            }
        }
    }

    // Per-thread reduce: packed (even,odd) top-2 -> fp32 (top1, top2).
    auto reduce2 = [](h2 m1v, h2 m2v, float& hi, float& sec) {
        float p = (float)m1v.x, q = (float)m1v.y;   // tops (p>=r, q>=s)
        float r = (float)m2v.x, s = (float)m2v.y;
        hi  = fmaxf(p, q);
        sec = fmaxf(fminf(p, q), fmaxf(r, s));
    };
    float hia, seca, hib, secb;
    reduce2(m1a, m2a, hia, seca);
    reduce2(m1b, m2b, hib, secb);

    hi_s[w][lane]      = hia;  se_s[w][lane]      = seca;
    hi_s[w][lane + 64] = hib;  se_s[w][lane + 64] = secb;
    __syncthreads();

    // Cross-wave merge and store (threads 0..99 own one t each).
    const int t = threadIdx.x;
    if (t < T_PTS) {
        float H1 = hi_s[0][t], H2 = se_s[0][t];
        #pragma unroll
        for (int wv = 1; wv < NWAVES; ++wv) {
            float h = hi_s[wv][t], s = se_s[wv][t];
            float lo = fminf(H1, h);           // loser of the top1 duel
            H1 = fmaxf(H1, h);
            H2 = fmaxf(fmaxf(H2, s), lo);
        }
        const size_t basei = (size_t)(bd * 2) * (CCH * T_PTS) + (size_t)c * T_PTS + t;
        out[basei]               = H1;
        out[basei + CCH * T_PTS] = H2;
    }
}

extern "C" void kernel_launch(void* const* d_in, const int* in_sizes, int n_in,
                              void* d_out, int out_size, void* d_ws, size_t ws_size,
                              hipStream_t stream) {
    const float* diagrams = (const float*)d_in[0];
    float* out = (float*)d_out;
    pl_topk_kernel<<<1024, NTHR, 0, stream>>>(diagrams, out);
}